// Round 15
// baseline (193.803 us; speedup 1.0000x reference)
//
#include <hip/hip_runtime.h>
#include <hip/hip_bf16.h>

// Dims fixed by setup_inputs(): b=8, t=64, s=512, qu=vu=d=512.
#define B_  8
#define T_  64
#define S_  512
#define D_  512

#define QN (512 * 512)      // qproj elements (B*T x D)
#define KN (4096 * 512)     // kTb elements (B x D x S)

#define TLOG2E 2.8853900817779268f   // 2*log2(e)
#define LOG2E  1.4426950408889634f

typedef __attribute__((ext_vector_type(8))) short bf16x8;
typedef __attribute__((ext_vector_type(4))) float f32x4;

__device__ __forceinline__ unsigned int pk2(float a, float b) {
    float2 f; f.x = a; f.y = b;
    __hip_bfloat162 h = __float22bfloat162_rn(f);
    return *(unsigned int*)&h;
}
#define BF2X(U) __uint_as_float((U) << 16)
#define BF2Y(U) __uint_as_float((U) & 0xffff0000u)

// ---------------------------------------------------------------------------
// MEGA kernel: projections + device barrier + fused attention in ONE launch.
// Grid 256 x 1024 thr. LDS 59520 B (58.1 KB) -> 2 blocks/CU capacity >= 256
// blocks -> all blocks co-resident (required for the spin barrier).
//
// Phase A: 4 teams of 4 waves per block; 64x64 tiles, BK=32, 16 lockstep
//   iterations (all teams identical trip count -> block-wide __syncthreads
//   works as a per-team barrier). XCD-pinned: block (r<<3|x):
//     r in [0,16):  team does k-tile batch x, local=r*4+team (tml=l>>3,tn=l&7)
//     r == 16/17:   team does q-tile (tm=x, tn=team / 4+team)
//     r >= 18:      idle (hits barriers only)
//   k-epilogue: kTb[b][d][s] bf16 transposed; q-epilogue: qproj f32 +bias.
//   Both scaled by 2log2e (same arithmetic as R14 -> bit-identical output).
//
// Device barrier: __syncthreads; thread0: __threadfence (wbL2) + RELEASE
//   atomicAdd(ctr); acquire-spin until ctr==256 (invL2 -> cross-XCD safe,
//   G16). Bounded spin (1e8) -> garbage+visible fail instead of hang.
//   ctr zeroed each call by hipMemsetAsync (graph-legal).
//
// Phase B: R14 fused_attn body verbatim, LDS overlaid on phase-A smem.
// ---------------------------------------------------------------------------
__global__ __launch_bounds__(1024, 4) void mega(
    const float* __restrict__ query, const float* __restrict__ value,
    const float* __restrict__ W1, const float* __restrict__ W2,
    const float* __restrict__ b1, const float* __restrict__ b2,
    const int*  __restrict__ mask, const float* __restrict__ scale,
    float* __restrict__ qproj, unsigned short* __restrict__ kTb,
    unsigned int* __restrict__ ctr,
    float* __restrict__ ctx, float* __restrict__ attn)
{
    // Layout: phase A teams at [0, 40960); phase B overlay (after barrier):
    // q0A@0 dA@2048 cA@4096 pex@6144 wp2@22528 part@26624 red2@59392
    __shared__ __align__(16) char smem[59520];

    const int tid = threadIdx.x;      // 0..1023
    const int blk = blockIdx.x;
    const int x = blk & 7;            // XCD / batch
    const int r = blk >> 3;           // 0..31

    // ================= Phase A: projection GEMMs ==========================
    {
        const int team = tid >> 8;    // 0..3
        const int ttid = tid & 255;

        int kind = 0, tmt = 0, tnt = 0;      // 0=idle 1=k 2=q
        if (r < 16)       { kind = 1; int l = r * 4 + team; tmt = x * 8 + (l >> 3); tnt = l & 7; }
        else if (r == 16) { kind = 2; tmt = x; tnt = team; }
        else if (r == 17) { kind = 2; tmt = x; tnt = 4 + team; }

        const float* A = (kind == 2) ? query : value;
        const float* W = (kind == 2) ? W1 : W2;

        unsigned short (*Ab)[40] = (unsigned short(*)[40])(smem + team * 10240);
        unsigned short (*Bs)[40] = (unsigned short(*)[40])(smem + team * 10240 + 5120);

        const int twid = ttid >> 6;
        const int lane = ttid & 63;
        const int wm = (twid & 1) * 32, wn = (twid >> 1) * 32;
        const int fm = lane & 15, fq = lane >> 4;

        f32x4 acc00 = {0.f, 0.f, 0.f, 0.f};
        f32x4 acc01 = acc00, acc10 = acc00, acc11 = acc00;

        const int ar = ttid >> 2;          // 0..63
        const int ac = (ttid & 3) * 8;     // 0,8,16,24
        const float* Ag = A + (size_t)(tmt * 64 + ar) * 512 + ac;
        const int c0 = (ttid & 15) * 4;    // 0..60
        const int kp = (ttid >> 4) * 2;    // 0..30
        const float* Wg = W + (size_t)kp * 512 + tnt * 64 + c0;

        float4 av0, av1, wv0, wv1;
        if (kind) {
            av0 = *(const float4*)(Ag);
            av1 = *(const float4*)(Ag + 4);
            wv0 = *(const float4*)(Wg);
            wv1 = *(const float4*)(Wg + 512);
        }

        for (int i = 0; i < 16; ++i) {
            if (kind) {
                uint4 pa;
                pa.x = pk2(av0.x, av0.y); pa.y = pk2(av0.z, av0.w);
                pa.z = pk2(av1.x, av1.y); pa.w = pk2(av1.z, av1.w);
                *(uint4*)&Ab[ar][ac] = pa;
                *(unsigned int*)&Bs[c0 + 0][kp] = pk2(wv0.x, wv1.x);
                *(unsigned int*)&Bs[c0 + 1][kp] = pk2(wv0.y, wv1.y);
                *(unsigned int*)&Bs[c0 + 2][kp] = pk2(wv0.z, wv1.z);
                *(unsigned int*)&Bs[c0 + 3][kp] = pk2(wv0.w, wv1.w);
            }
            __syncthreads();
            if (kind) {
                bf16x8 a0  = *(const bf16x8*)&Ab[wm + fm][fq * 8];
                bf16x8 a1  = *(const bf16x8*)&Ab[wm + 16 + fm][fq * 8];
                bf16x8 b0  = *(const bf16x8*)&Bs[wn + fm][fq * 8];
                bf16x8 b1v = *(const bf16x8*)&Bs[wn + 16 + fm][fq * 8];
                if (i < 15) {
                    const int kn = (i + 1) * 32;
                    av0 = *(const float4*)(Ag + kn);
                    av1 = *(const float4*)(Ag + kn + 4);
                    wv0 = *(const float4*)(Wg + (size_t)kn * 512);
                    wv1 = *(const float4*)(Wg + (size_t)kn * 512 + 512);
                }
                acc00 = __builtin_amdgcn_mfma_f32_16x16x32_bf16(a0, b0,  acc00, 0, 0, 0);
                acc01 = __builtin_amdgcn_mfma_f32_16x16x32_bf16(a0, b1v, acc01, 0, 0, 0);
                acc10 = __builtin_amdgcn_mfma_f32_16x16x32_bf16(a1, b0,  acc10, 0, 0, 0);
                acc11 = __builtin_amdgcn_mfma_f32_16x16x32_bf16(a1, b1v, acc11, 0, 0, 0);
            }
            __syncthreads();
        }

        // Epilogues (C/D layout m89-verified: col=lane&15, row=fq*4+reg)
        if (kind == 2) {
            const int n0 = tnt * 64 + wn + fm;
            const int n1 = n0 + 16;
            const int m0 = tmt * 64 + wm + fq * 4;
            float bias0 = b1[n0] + b2[n0];
            float bias1 = b1[n1] + b2[n1];
#pragma unroll
            for (int rr = 0; rr < 4; ++rr) {
                qproj[(size_t)(m0 + rr) * 512 + n0]      = (acc00[rr] + bias0) * TLOG2E;
                qproj[(size_t)(m0 + rr) * 512 + n1]      = (acc01[rr] + bias1) * TLOG2E;
                qproj[(size_t)(m0 + 16 + rr) * 512 + n0] = (acc10[rr] + bias0) * TLOG2E;
                qproj[(size_t)(m0 + 16 + rr) * 512 + n1] = (acc11[rr] + bias1) * TLOG2E;
            }
        } else if (kind == 1) {
            const int n0 = tnt * 64 + wn + fm;
            const int n1 = n0 + 16;
            const int m0 = tmt * 64 + wm + fq * 4;
            const int bb = m0 >> 9;
            const int sl = m0 & 511;
            unsigned short* kb = kTb + (size_t)(bb * 512) * 512;
            uint2 o;
            o.x = pk2(acc00[0] * TLOG2E, acc00[1] * TLOG2E);
            o.y = pk2(acc00[2] * TLOG2E, acc00[3] * TLOG2E);
            *(uint2*)(kb + (size_t)n0 * 512 + sl) = o;
            o.x = pk2(acc10[0] * TLOG2E, acc10[1] * TLOG2E);
            o.y = pk2(acc10[2] * TLOG2E, acc10[3] * TLOG2E);
            *(uint2*)(kb + (size_t)n0 * 512 + sl + 16) = o;
            o.x = pk2(acc01[0] * TLOG2E, acc01[1] * TLOG2E);
            o.y = pk2(acc01[2] * TLOG2E, acc01[3] * TLOG2E);
            *(uint2*)(kb + (size_t)n1 * 512 + sl) = o;
            o.x = pk2(acc11[0] * TLOG2E, acc11[1] * TLOG2E);
            o.y = pk2(acc11[2] * TLOG2E, acc11[3] * TLOG2E);
            *(uint2*)(kb + (size_t)n1 * 512 + sl + 16) = o;
        }
    }

    // ================= Device-wide barrier ================================
    __syncthreads();                   // drains each wave's stores (vmcnt 0)
    if (tid == 0) {
        __threadfence();               // agent fence: write back L2
        __hip_atomic_fetch_add(ctr, 1u, __ATOMIC_RELEASE, __HIP_MEMORY_SCOPE_AGENT);
        unsigned int v; unsigned long it = 0;
        do {
            v = __hip_atomic_load(ctr, __ATOMIC_ACQUIRE, __HIP_MEMORY_SCOPE_AGENT);
            if (v >= 256u) break;
            __builtin_amdgcn_s_sleep(2);
        } while (++it < 100000000ul);  // bounded: fail visibly, never hang
    }
    __syncthreads();

    // ================= Phase B: fused attention (R14 body) ================
    {
        const int b  = x;
        const int tp = r;
        const size_t row0 = (size_t)(b * T_ + tp * 2);

        float*  q0A = (float*)(smem);
        float*  dA  = (float*)(smem + 2048);
        float*  cA  = (float*)(smem + 4096);
        float4 (*pex)[256]      = (float4(*)[256])(smem + 6144);
        float2* wp2 = (float2*)(smem + 22528);
        float4 (*part)[8][128]  = (float4(*)[8][128])(smem + 26624);
        float2* red2 = (float2*)(smem + 59392);

        const int lane = tid & 63;
        const int wid  = tid >> 6;

        // Phase 0: q0 / delta / scale into LDS
        if (tid < 512) {
            float q0v = qproj[row0 * D_ + tid];
            float q1v = qproj[(row0 + 1) * D_ + tid];
            q0A[tid] = q0v;
            dA[tid]  = __builtin_amdgcn_exp2f(q1v - q0v);
            cA[tid]  = scale[tid];
        }
        __syncthreads();

        // Phase 1: thread (sp, dq), bf16 kTb
        const int sp  = tid & 255;
        const int dq  = tid >> 8;
        const int dlo = dq * 128;
        const unsigned short* kb = kTb + ((size_t)(b * 512 + dlo)) * 512 + sp * 2;

        float p00 = 0.f, p10 = 0.f, p01 = 0.f, p11 = 0.f;

        unsigned int nf0 = *(const unsigned int*)(kb);
        unsigned int nf1 = *(const unsigned int*)(kb + 512);
        unsigned int nf2 = *(const unsigned int*)(kb + 1024);
        unsigned int nf3 = *(const unsigned int*)(kb + 1536);

#define SC2(KU, QV, DV, CV) do {                                              \
        float e0 = __builtin_amdgcn_exp2f((QV) + BF2X(KU));                   \
        float ra = __builtin_amdgcn_rcpf(e0 + 1.0f);                          \
        float rb = __builtin_amdgcn_rcpf(fmaf(e0, (DV), 1.0f));               \
        p00 = fmaf((CV), ra, p00); p10 = fmaf((CV), rb, p10);                 \
        float e1 = __builtin_amdgcn_exp2f((QV) + BF2Y(KU));                   \
        float rc = __builtin_amdgcn_rcpf(e1 + 1.0f);                          \
        float rd = __builtin_amdgcn_rcpf(fmaf(e1, (DV), 1.0f));               \
        p01 = fmaf((CV), rc, p01); p11 = fmaf((CV), rd, p11);                 \
    } while (0)

        for (int g = 0; g < 32; ++g) {
            unsigned int kf0 = nf0, kf1 = nf1, kf2 = nf2, kf3 = nf3;
            const unsigned short* nb = kb + (size_t)(((g + 1) & 31) * 4) * 512;
            nf0 = *(const unsigned int*)(nb);
            nf1 = *(const unsigned int*)(nb + 512);
            nf2 = *(const unsigned int*)(nb + 1024);
            nf3 = *(const unsigned int*)(nb + 1536);
            const int d0 = dlo + g * 4;
            float4 q4 = *(const float4*)&q0A[d0];
            float4 dl = *(const float4*)&dA[d0];
            float4 c4 = *(const float4*)&cA[d0];
            SC2(kf0, q4.x, dl.x, c4.x);
            SC2(kf1, q4.y, dl.y, c4.y);
            SC2(kf2, q4.z, dl.z, c4.z);
            SC2(kf3, q4.w, dl.w, c4.w);
        }
#undef SC2

        {
            float4 pq; pq.x = p00; pq.y = p10; pq.z = p01; pq.w = p11;
            pex[dq][sp] = pq;
        }
        __syncthreads();

        // Phase 2: softmax (waves 0-7), barriers block-wide
        float x0 = 0.f, x1 = 0.f;
        if (tid < 512) {
            const int s = tid;
            const int s2 = s >> 1;
            const bool odd = (s & 1) != 0;
            float4 r0 = pex[0][s2], r1 = pex[1][s2];
            float4 r2 = pex[2][s2], r3 = pex[3][s2];
            float pt0 = odd ? ((r0.z + r1.z) + (r2.z + r3.z))
                            : ((r0.x + r1.x) + (r2.x + r3.x));
            float pt1 = odd ? ((r0.w + r1.w) + (r2.w + r3.w))
                            : ((r0.y + r1.y) + (r2.y + r3.y));
            const int m = mask[b * S_ + s];
            x0 = m ? (-2.0f * pt0) : -1e9f;
            x1 = m ? (-2.0f * pt1) : -1e9f;
            float2 mx; mx.x = x0; mx.y = x1;
#pragma unroll
            for (int off = 32; off >= 1; off >>= 1) {
                mx.x = fmaxf(mx.x, __shfl_xor(mx.x, off));
                mx.y = fmaxf(mx.y, __shfl_xor(mx.y, off));
            }
            if (lane == 0) red2[wid] = mx;
        }
        __syncthreads();

        float e0 = 0.f, e1 = 0.f;
        if (tid < 512) {
            float2 M = red2[0];
#pragma unroll
            for (int i = 1; i < 8; ++i) {
                M.x = fmaxf(M.x, red2[i].x);
                M.y = fmaxf(M.y, red2[i].y);
            }
            e0 = __builtin_amdgcn_exp2f((x0 - M.x) * LOG2E);
            e1 = __builtin_amdgcn_exp2f((x1 - M.y) * LOG2E);
            float2 sm; sm.x = e0; sm.y = e1;
#pragma unroll
            for (int off = 32; off >= 1; off >>= 1) {
                sm.x += __shfl_xor(sm.x, off);
                sm.y += __shfl_xor(sm.y, off);
            }
            if (lane == 0) red2[8 + wid] = sm;
        }
        __syncthreads();

        if (tid < 512) {
            const int s = tid;
            float2 SS = red2[8];
#pragma unroll
            for (int i = 9; i < 16; ++i) {
                SS.x += red2[i].x;
                SS.y += red2[i].y;
            }
            const float w0 = e0 * __builtin_amdgcn_rcpf(SS.x);
            const float w1 = e1 * __builtin_amdgcn_rcpf(SS.y);
            float2 wpair; wpair.x = w0; wpair.y = w1;
            wp2[s] = wpair;
            attn[row0 * S_ + s]       = w0;
            attn[(row0 + 1) * S_ + s] = w1;
        }
        __syncthreads();

        // Phase 3: context, all 16 waves
        const int g  = tid >> 7;
        const int v4 = tid & 127;
        const float* vb = value + ((size_t)(b * S_) + g * 64) * D_ + v4 * 4;
        float4 a0; a0.x = 0.f; a0.y = 0.f; a0.z = 0.f; a0.w = 0.f;
        float4 a1 = a0;
#pragma unroll 4
        for (int i = 0; i < 64; ++i) {
            float4 vv = *(const float4*)(vb + (size_t)i * D_);
            float2 w = wp2[g * 64 + i];
            a0.x = fmaf(w.x, vv.x, a0.x); a0.y = fmaf(w.x, vv.y, a0.y);
            a0.z = fmaf(w.x, vv.z, a0.z); a0.w = fmaf(w.x, vv.w, a0.w);
            a1.x = fmaf(w.y, vv.x, a1.x); a1.y = fmaf(w.y, vv.y, a1.y);
            a1.z = fmaf(w.y, vv.z, a1.z); a1.w = fmaf(w.y, vv.w, a1.w);
        }
        part[0][g][v4] = a0;
        part[1][g][v4] = a1;
        __syncthreads();
        if (tid < 256) {
            const int t = tid >> 7, v = tid & 127;
            float4 o; o.x = 0.f; o.y = 0.f; o.z = 0.f; o.w = 0.f;
#pragma unroll
            for (int gg = 0; gg < 8; ++gg) {
                float4 p = part[t][gg][v];
                o.x += p.x; o.y += p.y; o.z += p.z; o.w += p.w;
            }
            *(float4*)(ctx + (row0 + t) * D_ + v * 4) = o;
        }
    }
}

extern "C" void kernel_launch(void* const* d_in, const int* in_sizes, int n_in,
                              void* d_out, int out_size, void* d_ws, size_t ws_size,
                              hipStream_t stream) {
    const float* query = (const float*)d_in[0];
    const float* value = (const float*)d_in[1];
    const int*   mask  = (const int*)  d_in[2];
    const float* W1w   = (const float*)d_in[3];
    const float* W1b   = (const float*)d_in[4];
    const float* W2w   = (const float*)d_in[5];
    const float* W2b   = (const float*)d_in[6];
    const float* scale = (const float*)d_in[7];

    float* ctx  = (float*)d_out;
    float* attn = (float*)d_out + (size_t)B_ * T_ * D_;

    float* qproj = (float*)d_ws;                                   // 1 MB
    unsigned short* kTb = (unsigned short*)(qproj + (size_t)QN);   // 4 MB
    unsigned int* ctr = (unsigned int*)((char*)d_ws + (6u << 20)); // @6 MB

    hipMemsetAsync(ctr, 0, 4, stream);   // graph-legal; runs after ws poison
    mega<<<256, 1024, 0, stream>>>(query, value, W1w, W2w, W1b, W2b,
                                   mask, scale, qproj, kTb, ctr, ctx, attn);
}